// Round 9
// baseline (239.213 us; speedup 1.0000x reference)
//
#include <hip/hip_runtime.h>
#include <stdint.h>

// region_pooling via scatter + dense GEMM + split-k partials.
// F: [B=8, HW=4096, C=1024] fp32 (H=W=64); pc: [B, M=32, P=512, 2]
// out[b,m,c] = sum_hw W[b][hw][m] * F[b][hw][c]; W = scattered bilinear
// weights pre-scaled by 1/P.
//
// wgemm v7: W moved OFF the LDS pipe. R8's floor was LDS: 2 of 3
// ds_read_b128 per row-wave were broadcast W reads (~24 of 36 LDS cyc per
// 32 FMA). Now W is read via wave-uniform scalar loads (s_load -> SGPR,
// v_fmac v,s,v), LDS holds only the async-staged F double buffer (16 KB),
// and NKC=64 gives 2048 blocks = 8 blocks/CU = 32 waves/CU.

#define NB 8
#define NM 32
#define NP 512
#define NC 1024
#define NH 64
#define NHW 4096

#define NKC  64                   // k-split: blocks per (ct,b)
#define ROWS (NHW / NKC)          // 64 rows per block
#define KT   8                    // rows per sub-tile
#define NT   (ROWS / KT)          // 8 sub-tiles
#define NCT  4                    // c-tiles
#define CTW  256                  // channels per c-tile (1 float4/thread)

__device__ __forceinline__ void async16(const void* g, void* l) {
    __builtin_amdgcn_global_load_lds(
        (const __attribute__((address_space(1))) unsigned int*)g,
        (__attribute__((address_space(3))) unsigned int*)l,
        16, 0, 0);
}

// ---- Phase 1: scatter bilinear weights into W[b][hw][m] (pre-zeroed) ----
__global__ __launch_bounds__(256) void scatter_w(
    const float* __restrict__ pc, float* __restrict__ W)
{
    int idx = blockIdx.x * 256 + threadIdx.x;   // [0, B*M*P)
    int bm  = idx >> 9;                         // b*NM + m
    int m   = bm & (NM - 1);
    int b   = bm >> 5;

    float2 c = ((const float2*)pc)[idx];
    float y = c.x * 63.0f;
    float x = c.y * 63.0f;
    float x0f = floorf(x), y0f = floorf(y);
    float wx = x - x0f, wy = y - y0f;
    int ix0 = min(max((int)x0f, 0), 63);
    int ix1 = min(ix0 + 1, 63);
    int iy0 = min(max((int)y0f, 0), 63);
    int iy1 = min(iy0 + 1, 63);
    float wx1 = 1.0f - wx, wy1 = 1.0f - wy;
    const float s = 1.0f / (float)NP;           // fold the mean here

    float* Wb = W + (size_t)b * (NHW * NM) + m;
    atomicAdd(Wb + ((iy0 * NH + ix0) * NM), wx1 * wy1 * s);
    atomicAdd(Wb + ((iy0 * NH + ix1) * NM), wx  * wy1 * s);
    atomicAdd(Wb + ((iy1 * NH + ix0) * NM), wx1 * wy  * s);
    atomicAdd(Wb + ((iy1 * NH + ix1) * NM), wx  * wy  * s);
}

// ---- Phase 2: P[kc][b][m][c] = sum_{rows of chunk} W[b][hw][m]*F[b][hw][c]
// grid (NKC, NCT, NB) = 2048 blocks; 256 thr = 4 waves; 16 KB LDS.
// wave w -> m-octet [8w, 8w+8) via scalar W loads; lane -> ch ct*256+4*lane.
__global__ __launch_bounds__(256) void wgemm(
    const float* __restrict__ W, const float* __restrict__ F,
    float* __restrict__ P)
{
    __shared__ float4 sF[2][KT * CTW / 4];      // 2 x 8 KB (8 rows x 256 ch)

    const int kc   = blockIdx.x;
    const int ct   = blockIdx.y;
    const int b    = blockIdx.z;
    const int tid  = threadIdx.x;
    const int wav  = __builtin_amdgcn_readfirstlane(tid >> 6);  // uniform
    const int lane = tid & 63;
    const int hw0  = kc * ROWS;
    const int c0   = ct * CTW + lane * 4;
    const int lane16 = lane * 16;

    // wave-uniform W base: this wave's m-octet, rows hw0..hw0+ROWS
    const float* __restrict__ Wu = W + ((size_t)b * NHW + hw0) * NM + wav * 8;
    const char* Fg = (const char*)(F + ((size_t)b * NHW + hw0) * NC + ct * CTW);

    // stage F sub-tile t (8 rows x 1 KB): 8 issues, 2 per wave
    auto stage_f = [&](int t, int buf) {
        char* lds = (char*)sF[buf];
#pragma unroll
        for (int i = 0; i < 2; ++i) {
            int j = wav * 2 + i;                // row 0..7
            async16(Fg + (size_t)(t * KT + j) * (NC * 4) + lane16,
                    lds + j * 1024 + lane16);
        }
    };

    stage_f(0, 0);
    __syncthreads();                            // drains vmcnt: sub-tile 0

    float4 acc[8];
#pragma unroll
    for (int m = 0; m < 8; ++m) acc[m] = make_float4(0.f, 0.f, 0.f, 0.f);

    for (int t = 0; t < NT; ++t) {
        if (t + 1 < NT) stage_f(t + 1, (t + 1) & 1);  // async, drained at barrier
        const float4* fb = sF[t & 1];
#pragma unroll
        for (int r = 0; r < KT; ++r) {
            float4 f = fb[r * 64 + lane];
            const float* __restrict__ wr = Wu + (size_t)(t * KT + r) * NM; // uniform
#pragma unroll
            for (int m = 0; m < 8; ++m) {
                float w = wr[m];                // s_load: wave-uniform addr
                acc[m].x = fmaf(w, f.x, acc[m].x);
                acc[m].y = fmaf(w, f.y, acc[m].y);
                acc[m].z = fmaf(w, f.z, acc[m].z);
                acc[m].w = fmaf(w, f.w, acc[m].w);
            }
        }
        __syncthreads();
    }

    // partials: P[kc][b][m][c]
    float* pb = P + (((size_t)kc * NB + b) * NM + wav * 8) * NC + c0;
#pragma unroll
    for (int m = 0; m < 8; ++m)
        *(float4*)(pb + (size_t)m * NC) = acc[m];
}

// ---- Phase 3: out = sum over the 64 k-chunk partials ----
__global__ __launch_bounds__(256) void reduce_p(
    const float* __restrict__ P, float* __restrict__ out)
{
    const int idx = blockIdx.x * 256 + threadIdx.x;   // [0, NB*NM*NC/4)
    const float4* p4 = (const float4*)P;
    const int stride = NB * NM * NC / 4;              // 65536
    float4 s0 = make_float4(0.f, 0.f, 0.f, 0.f);
    float4 s1 = make_float4(0.f, 0.f, 0.f, 0.f);
#pragma unroll 8
    for (int kc = 0; kc < NKC; kc += 2) {
        float4 a = p4[(size_t)kc * stride + idx];
        float4 c = p4[(size_t)(kc + 1) * stride + idx];
        s0.x += a.x; s0.y += a.y; s0.z += a.z; s0.w += a.w;
        s1.x += c.x; s1.y += c.y; s1.z += c.z; s1.w += c.w;
    }
    ((float4*)out)[idx] = make_float4(s0.x + s1.x, s0.y + s1.y,
                                      s0.z + s1.z, s0.w + s1.w);
}

// ---- Fallback (ws too small): direct gather ----
__global__ __launch_bounds__(256) void region_pool_direct(
    const float* __restrict__ fm, const float* __restrict__ pc,
    float* __restrict__ out)
{
    __shared__ int4   sIdx[NP];
    __shared__ float4 sWv[NP];
    const int bid = blockIdx.x;
    const int b   = bid >> 5;
    const int tid = threadIdx.x;
    const float2* pc2 = (const float2*)(pc + (size_t)bid * NP * 2);
    for (int p = tid; p < NP; p += 256) {
        float2 c = pc2[p];
        float y = c.x * 63.0f, x = c.y * 63.0f;
        float x0f = floorf(x), y0f = floorf(y);
        float wx = x - x0f, wy = y - y0f;
        int ix0 = min(max((int)x0f, 0), 63);
        int ix1 = min(ix0 + 1, 63);
        int iy0 = min(max((int)y0f, 0), 63);
        int iy1 = min(iy0 + 1, 63);
        sIdx[p] = make_int4((iy0 * NH + ix0) << 10, (iy0 * NH + ix1) << 10,
                            (iy1 * NH + ix0) << 10, (iy1 * NH + ix1) << 10);
        float wx1 = 1.0f - wx, wy1 = 1.0f - wy;
        sWv[p] = make_float4(wx1 * wy1, wx * wy1, wx1 * wy, wx * wy);
    }
    __syncthreads();
    const float* Fb = fm + (size_t)b * (NHW * NC) + tid * 4;
    float4 acc = make_float4(0.f, 0.f, 0.f, 0.f);
#pragma unroll 4
    for (int p = 0; p < NP; ++p) {
        int4 off = sIdx[p]; float4 w = sWv[p];
        float4 f00 = *(const float4*)(Fb + off.x);
        float4 f01 = *(const float4*)(Fb + off.y);
        float4 f10 = *(const float4*)(Fb + off.z);
        float4 f11 = *(const float4*)(Fb + off.w);
        acc.x = fmaf(w.x, f00.x, fmaf(w.y, f01.x, fmaf(w.z, f10.x, fmaf(w.w, f11.x, acc.x))));
        acc.y = fmaf(w.x, f00.y, fmaf(w.y, f01.y, fmaf(w.z, f10.y, fmaf(w.w, f11.y, acc.y))));
        acc.z = fmaf(w.x, f00.z, fmaf(w.y, f01.z, fmaf(w.z, f10.z, fmaf(w.w, f11.z, acc.z))));
        acc.w = fmaf(w.x, f00.w, fmaf(w.y, f01.w, fmaf(w.z, f10.w, fmaf(w.w, f11.w, acc.w))));
    }
    const float inv = 1.0f / (float)NP;
    ((float4*)(out + (size_t)bid * NC))[tid] =
        make_float4(acc.x * inv, acc.y * inv, acc.z * inv, acc.w * inv);
}

extern "C" void kernel_launch(void* const* d_in, const int* in_sizes, int n_in,
                              void* d_out, int out_size, void* d_ws, size_t ws_size,
                              hipStream_t stream) {
    const float* fm = (const float*)d_in[0];   // [8, 4096, 1024]
    const float* pc = (const float*)d_in[1];   // [8, 32, 512, 2]
    float* out = (float*)d_out;                // [8, 32, 1, 1024]

    const size_t wbytes = (size_t)NB * NHW * NM * sizeof(float);           // 4 MB
    const size_t pbytes = (size_t)NKC * NB * NM * NC * sizeof(float);      // 64 MB
    if (ws_size >= wbytes + pbytes) {
        float* W = (float*)d_ws;
        float* P = (float*)((char*)d_ws + wbytes);
        hipMemsetAsync(W, 0, wbytes, stream);
        scatter_w<<<(NB * NM * NP) / 256, 256, 0, stream>>>(pc, W);
        dim3 grid(NKC, NCT, NB);
        wgemm<<<grid, 256, 0, stream>>>(W, fm, P);
        reduce_p<<<(NB * NM * NC / 4) / 256, 256, 0, stream>>>(P, out);
    } else {
        region_pool_direct<<<NB * NM, 256, 0, stream>>>(fm, pc, out);
    }
}